// Round 4
// baseline (3088.313 us; speedup 1.0000x reference)
//
#include <hip/hip_runtime.h>
#include <cstdint>
#include <cstddef>

typedef unsigned short u16;
typedef __attribute__((ext_vector_type(8))) short short8;
typedef __attribute__((ext_vector_type(4))) float f32x4;

#define SEQ 128
#define BATCH 256
#define HID 1024
#define LSZ 262144

#define MFMA(a,b,c) __builtin_amdgcn_mfma_f32_16x16x32_bf16((a),(b),(c),0,0,0)

// global -> LDS direct (16B/lane, wave-uniform LDS base + lane*16).
// aux 17 = sc0|sc1 (system-coherent, bypass stale L2); aux 0 = cached.
#define GLDS_CG(g, l) __builtin_amdgcn_global_load_lds( \
  (__attribute__((address_space(1))) void*)(uintptr_t)(const void*)(g), \
  (__attribute__((address_space(3))) void*)(unsigned)(uintptr_t)(void*)(l), 16, 0, 17)
#define GLDS_NC(g, l) __builtin_amdgcn_global_load_lds( \
  (__attribute__((address_space(1))) void*)(uintptr_t)(const void*)(g), \
  (__attribute__((address_space(3))) void*)(unsigned)(uintptr_t)(void*)(l), 16, 0, 0)

__device__ __forceinline__ u16 f2b(float f) {
  union { float f; unsigned u; } v; v.f = f;
  unsigned r = (v.u + 0x7FFFu + ((v.u >> 16) & 1u)) >> 16;
  return (u16)r;
}
__device__ __forceinline__ float b2f(u16 h) {
  union { unsigned u; float f; } v; v.u = ((unsigned)h) << 16; return v.f;
}
__device__ __forceinline__ float sigm(float x){ return 1.f/(1.f + __expf(-x)); }
__device__ __forceinline__ float tanh_f(float x){
  x = fminf(15.f, fmaxf(-15.f, x));
  float e = __expf(2.f*x); return (e-1.f)/(e+1.f);
}
__device__ __forceinline__ float eluf(float x){ return x > 0.f ? x : expm1f(x); }

__device__ __forceinline__ void store_cg(u16* p, short8 v) {
  asm volatile("global_store_dwordx4 %0, %1, off sc0 sc1" :: "v"(p), "v"(v) : "memory");
}
__device__ __forceinline__ void wait_vm0() {
  asm volatile("s_waitcnt vmcnt(0)" ::: "memory");
}
__device__ __forceinline__ void waitgroup(int* f, int tgt) {
  if (threadIdx.x < 64) {
    int idx = threadIdx.x & 31;
    while (__hip_atomic_load(f + idx, __ATOMIC_RELAXED, __HIP_MEMORY_SCOPE_AGENT) < tgt)
      __builtin_amdgcn_s_sleep(1);
  }
  __syncthreads();
}

// ---------------- workspace layout (bytes) ----------------
static const size_t OFF_W0F  = 0;           // 32cg*34kb*8ct*512*2 = 8912896
static const size_t OFF_W1F  = 8912896;     // 32*64*8*512*2 = 16777216
static const size_t OFF_XF   = 25690112;    // 128t*16grt*2kb*512*2 = 4194304
static const size_t OFF_H0U  = 29884416;    // 2 slots * 524288 (UNMASKED h0, for L1 input)
static const size_t OFF_C0   = 30932992;    // fp32 256x1024
static const size_t OFF_C1   = 31981568;
static const size_t OFF_H1U  = 33030144;    // 129 slots * 524288 (slot t+1 == hs[t], unmasked)
static const size_t OFF_BS0  = 100663296;
static const size_t OFF_BS1  = 100679680;
static const size_t OFF_FLG  = 100696064;   // 256 ints
static const size_t OFF_MU   = 100697088;
static const size_t OFF_RSTD = 100828160;
static const size_t OFF_W1LN = 100959232;
static const size_t OFF_S1   = 102007808;
static const size_t OFF_B1P  = 102009856;
static const size_t OFF_W2B  = 102011904;
static const size_t OFF_W3B  = 102142976;
static const size_t OFF_A1   = 102159360;   // 33554432 -> end 135713792
static const size_t OFF_A2   = 0;           // alias dead w0f (post-lstm)
static const size_t OFF_A3   = 8912896;     // alias dead w1f (post-lstm)
// masked-h rings alias the A1 region (A1 written only after lstm completes)
static const size_t OFF_H0M  = 102159360;            // 2 slots * 524288
static const size_t OFF_H1M  = 102159360 + 1048576;  // 2 slots * 524288

// ---------------- prep: weights into fragment-linear tiles ----------------
__global__ void prep_wf(const float* __restrict__ wih, const float* __restrict__ whh,
                        u16* __restrict__ out, int nkb, int kx) {
  int b = blockIdx.x; int cg = b >> 3, ct = b & 7;
  int g = ct >> 1;
  int n = nkb << 9;
  for (int e = threadIdx.x; e < n; e += 256) {
    int kb = e >> 9, r = e & 511;
    int q = r >> 7, col16 = (r >> 3) & 15, j = r & 7;
    int hl = (ct & 1) * 16 + col16;
    int gr = g * HID + cg * 32 + hl;
    int k = kb * 32 + q * 8 + j;
    float w = (k < kx) ? wih[(size_t)gr * kx + k] : whh[(size_t)gr * HID + (k - kx)];
    out[((size_t)(cg * nkb + kb) * 8 + ct) * 512 + r] = f2b(w);
  }
}

__global__ void prep_w1ln(const float* __restrict__ w1, const float* __restrict__ lng,
                          const float* __restrict__ lnb, const float* __restrict__ b1,
                          u16* __restrict__ w1ln, float* __restrict__ S1, float* __restrict__ b1p) {
  int j = blockIdx.x;
  float s = 0.f, bb = 0.f;
  for (int k = threadIdx.x; k < HID; k += 256) {
    float w = w1[(size_t)j * HID + k];
    u16 q = f2b(w * lng[k]);
    w1ln[(size_t)j * HID + k] = q;
    s += b2f(q);
    bb += w * lnb[k];
  }
  __shared__ float r1[256], r2[256];
  r1[threadIdx.x] = s; r2[threadIdx.x] = bb;
  __syncthreads();
  for (int o = 128; o > 0; o >>= 1) {
    if (threadIdx.x < (unsigned)o) { r1[threadIdx.x] += r1[threadIdx.x+o]; r2[threadIdx.x] += r2[threadIdx.x+o]; }
    __syncthreads();
  }
  if (threadIdx.x == 0) { S1[j] = r1[0]; b1p[j] = b1[j] + r2[0]; }
}

__global__ void prep_misc(const float* bih0, const float* bhh0, const float* bih1, const float* bhh1,
                          const float* x, const float* h0in, const float* c0in,
                          const float* w2, const float* w3, const int* done,
                          float* bs0, float* bs1, u16* xf, u16* h0m, u16* h1m,
                          float* c0buf, float* c1buf, u16* w2b, u16* w3b, int* flg) {
  size_t i = (size_t)blockIdx.x * blockDim.x + threadIdx.x;
  if (i < 4096) { bs0[i] = bih0[i] + bhh0[i]; return; }
  i -= 4096;
  if (i < 4096) { bs1[i] = bih1[i] + bhh1[i]; return; }
  i -= 4096;
  if (i < 2097152) {
    int o = (int)i;
    int r = o & 511, tile = o >> 9;
    int q = r >> 7, rl = (r >> 3) & 15, j = r & 7;
    int kb = tile & 1, v = tile >> 1;
    int grt = v & 15, t = v >> 4;
    int row = grt * 16 + rl, k = kb * 32 + q * 8 + j;
    xf[o] = f2b(x[((size_t)t * BATCH + row) * 64 + k]);
    return;
  }
  i -= 2097152;
  if (i < 262144) {   // h0m slot 0: MASKED initial h0 (layer0 recurrent input @ t=0)
    int o = (int)i;
    int r = o & 511, tile = o >> 9;
    int q = r >> 7, rl = (r >> 3) & 15, j = r & 7;
    int grt = tile >> 5, kb = tile & 31;
    int row = grt * 16 + rl, h = kb * 32 + q * 8 + j;
    h0m[o] = done[row] ? (u16)0 : f2b(h0in[(size_t)row * HID + h]);
    return;
  }
  i -= 262144;
  if (i < 262144) {   // h1m slot 0: MASKED initial h1 (layer1 recurrent input @ t=0)
    int o = (int)i;
    int r = o & 511, tile = o >> 9;
    int q = r >> 7, rl = (r >> 3) & 15, j = r & 7;
    int grt = tile >> 5, kb = tile & 31;
    int row = grt * 16 + rl, h = kb * 32 + q * 8 + j;
    h1m[o] = done[row] ? (u16)0 : f2b(h0in[LSZ + (size_t)row * HID + h]);
    return;
  }
  i -= 262144;
  if (i < LSZ) { c0buf[i] = c0in[i]; return; }
  i -= LSZ;
  if (i < LSZ) { c1buf[i] = c0in[LSZ + i]; return; }
  i -= LSZ;
  if (i < 65536) { w2b[i] = f2b(w2[i]); return; }
  i -= 65536;
  if (i < 8192) { w3b[i] = f2b(w3[i]); return; }
  i -= 8192;
  if (i < 256) { flg[i] = 0; return; }
}

// ---------------- persistent LSTM recurrence ----------------
// 256 blocks x 256 thr. bid = layer*128 + rg*32 + cg.
// block tile 64 rows x 128 gate-cols; wave wv owns 32-col slice (B dedup'd).
// Pipeline position p -> chunk ocmap(p):
//   L0: identity (9 chunks). L1: h1-part (oc 8..15) FIRST, then h0-part (oc 0..7);
//   the binding wait on L0's flag moves to position 6 (just before first h0 issue),
//   so 6 chunk-bodies of own-recurrence overlap L0's tail.
// L0's WAR wait (g1 >= t-1, guards only its h-stores) moves to just-before-epilogue,
// so L0's next-step chunks overlap L1's tail.
__global__ __launch_bounds__(256, 1) void lstm_persist(
    const u16* __restrict__ w0f, const u16* __restrict__ w1f, const u16* __restrict__ xf,
    u16* __restrict__ h0u, u16* __restrict__ h1u,
    u16* __restrict__ h0m, u16* __restrict__ h1m,
    float* __restrict__ c0b, float* __restrict__ c1b,
    const float* __restrict__ bs0, const float* __restrict__ bs1,
    const int* __restrict__ done, int* __restrict__ flg,
    float* __restrict__ dout)
{
  const int bid = blockIdx.x;
  const int layer = bid >> 7;
  const int rg = (bid >> 5) & 3;
  const int cg = bid & 31;
  const int tid = threadIdx.x;
  const int lane = tid & 63, wv = tid >> 6;
  const int quad = lane >> 4, c16 = lane & 15;
  const int NKB = layer ? 64 : 34;
  const int NC  = layer ? 16 : 9;
  const u16* Wf = layer ? w1f : w0f;
  const float* bs = layer ? bs1 : bs0;
  float* cb = layer ? c1b : c0b;
  int* fl0 = flg;
  int* fl1 = flg + 128;
  int* myf = (layer ? fl1 : fl0) + rg * 32 + cg;
  int* g0 = fl0 + rg * 32;
  int* g1 = fl1 + rg * 32;

  __shared__ __align__(16) u16 smem[32768];  // 4 x 16KB A buffers; epilogue gl aliases
  float* gl = (float*)smem;                  // 64 x 132 fp32 (padded stride)

  const short8 z8 = {0,0,0,0,0,0,0,0};

  for (int t = 0; t < SEQ; ++t) {
    // step-top: only the cheap same-group (sibling) waits remain here
    if (layer == 0) {
      if (t >= 1) waitgroup(g0, t);        // siblings' h0m(t-1) ready
    } else {
      if (t >= 1) waitgroup(g1, t);        // siblings' h1m(t-1) ready (also WAR for h1m)
    }

    // pipeline position -> chunk index
    auto ocmap = [&](int p) -> int {
      if (layer) return p >= 16 ? 7 : (p < 8 ? p + 8 : p - 8);
      return p > 8 ? 8 : p;
    };

    // A chunk: kb in [oc*4, oc*4+4); wave wv stages kbl=wv, 4 grt tiles.
    // LDS buf (p&3): tile (kbl,j) at u16 offset (kbl*4+j)*512.
    auto issueA = [&](int p) {
      int oc = ocmap(p);
      int kb = oc * 4 + wv; if (kb > NKB - 1) kb = NKB - 1;
      u16* lb = &smem[((unsigned)(p & 3)) * 8192 + (unsigned)wv * 2048];
      if (layer == 0) {
        if (kb < 2) {
          #pragma unroll
          for (int j = 0; j < 4; ++j) {
            const u16* g = xf + ((size_t)((t * 16 + rg * 4 + j) * 2 + kb)) * 512 + lane * 8;
            GLDS_NC(g, lb + j * 512);
          }
        } else {
          #pragma unroll
          for (int j = 0; j < 4; ++j) {
            const u16* g = h0m + (size_t)(t & 1) * 262144
                               + (size_t)((rg * 4 + j) * 32 + (kb - 2)) * 512 + lane * 8;
            GLDS_CG(g, lb + j * 512);
          }
        }
      } else {
        if (kb < 32) {
          #pragma unroll
          for (int j = 0; j < 4; ++j) {
            const u16* g = h0u + (size_t)((t + 1) & 1) * 262144
                               + (size_t)((rg * 4 + j) * 32 + kb) * 512 + lane * 8;
            GLDS_CG(g, lb + j * 512);
          }
        } else {
          #pragma unroll
          for (int j = 0; j < 4; ++j) {
            const u16* g = h1m + (size_t)(t & 1) * 262144
                               + (size_t)((rg * 4 + j) * 32 + (kb - 32)) * 512 + lane * 8;
            GLDS_CG(g, lb + j * 512);
          }
        }
      }
    };

    auto loadB = [&](int p, short8 (&vB)[4][2]) {
      int oc = ocmap(p);
      #pragma unroll
      for (int kbl = 0; kbl < 4; ++kbl) {
        int kb = oc * 4 + kbl; if (kb > NKB - 1) kb = NKB - 1;
        #pragma unroll
        for (int h = 0; h < 2; ++h)
          vB[kbl][h] = *(const short8*)(Wf + ((size_t)(cg * NKB + kb) * 8 + wv * 2 + h) * 512 + lane * 8);
      }
    };

    f32x4 acc[4][2];
    #pragma unroll
    for (int a = 0; a < 4; ++a) { acc[a][0] = (f32x4){0,0,0,0}; acc[a][1] = (f32x4){0,0,0,0}; }

    auto comp = [&](int p, short8 (&vB)[4][2]) {
      int oc = ocmap(p);
      int kbc = NKB - oc * 4; if (kbc > 4) kbc = 4;
      const u16* sb = &smem[((unsigned)(p & 3)) * 8192] + lane * 8;
      #pragma unroll
      for (int kbl = 0; kbl < 4; ++kbl) if (kbl < kbc) {
        #pragma unroll
        for (int a = 0; a < 4; ++a) {
          short8 af = *(const short8*)(sb + (kbl * 4 + a) * 512);
          acc[a][0] = MFMA(af, vB[kbl][0], acc[a][0]);
          acc[a][1] = MFMA(af, vB[kbl][1], acc[a][1]);
        }
      }
    };

    short8 vB0[4][2], vB1[4][2], vB2[4][2];

    // prologue: positions 0,1 (L1: oc 8,9 = own h1 recurrence -> no L0 dep)
    loadB(0, vB0); issueA(0);
    asm volatile("" ::: "memory");
    loadB(1, vB1); issueA(1);

    // steady state: 2 segments (24 loads) stay in flight across the wait.
    // L1 inserts the binding L0-flag wait at position 6 (first h0 issue is pos 6's p+2=8... 
    // ocmap(8)=0 -> first h0u issue happens in body 6, AFTER the wait).
#define CHUNK(CC, VBL, VBU) \
    if (layer && (CC) == 6) waitgroup(g0, t + 1); \
    loadB((CC) + 2, VBL); issueA((CC) + 2); \
    asm volatile("s_waitcnt vmcnt(24)" ::: "memory"); \
    __builtin_amdgcn_s_barrier(); \
    __builtin_amdgcn_sched_barrier(0); \
    comp((CC), VBU);

    int c = 0;
    for (;;) {
      CHUNK(c, vB2, vB0) if (++c == NC) break;
      CHUNK(c, vB0, vB1) if (++c == NC) break;
      CHUNK(c, vB1, vB2) if (++c == NC) break;
    }
#undef CHUNK

    // drain dummy prefetches before aliasing smem as gl; sync all waves' comp
    wait_vm0();
    __syncthreads();

    // epilogue: gates -> LDS gl[row64][132]; wave wv owns cols [wv*32, wv*32+32)
    #pragma unroll
    for (int a = 0; a < 4; ++a)
      #pragma unroll
      for (int ct = 0; ct < 2; ++ct)
        #pragma unroll
        for (int rgi = 0; rgi < 4; ++rgi)
          gl[(a * 16 + quad * 4 + rgi) * 132 + wv * 32 + ct * 16 + c16] = acc[a][ct][rgi];
    __syncthreads();

    // L0's WAR wait (guards only the h0u/h0m stores below): L1 must have finished
    // reading the slot we are about to overwrite (2-step slack; usually free).
    if (layer == 0 && t >= 2) waitgroup(g1, t - 1);

    {
      int row = tid >> 2;           // 0..63
      int q = tid & 3;
      int h8 = q * 8;
      int rowg = rg * 64 + row;
      int H0 = cg * 32 + h8;
      const float* glp = gl + row * 132;
      float m = done[t * BATCH + rowg] ? 0.f : 1.f;
      int nx = (t < SEQ - 1) ? done[(t + 1) * BATCH + rowg] : 0;
      float* cp = cb + (size_t)rowg * HID + H0;
      short8 hv;
      float h2a[8], c2a[8];
      #pragma unroll
      for (int j = 0; j < 8; ++j) {
        float ivv = glp[h8 + j]      + bs[H0 + j];
        float fvv = glp[32 + h8 + j] + bs[HID + H0 + j];
        float gvv = glp[64 + h8 + j] + bs[2*HID + H0 + j];
        float ovv = glp[96 + h8 + j] + bs[3*HID + H0 + j];
        float c2 = sigm(fvv) * (cp[j] * m) + sigm(ivv) * tanh_f(gvv);
        float h2 = sigm(ovv) * tanh_f(c2);
        cp[j] = c2;
        h2a[j] = h2; c2a[j] = c2;
        ((u16*)&hv)[j] = f2b(h2);
      }
      short8 hm = nx ? z8 : hv;
      size_t off = (size_t)((rg * 4 + (row >> 4)) * 32 + cg) * 512 + (size_t)(q * 16 + (row & 15)) * 8;
      if (layer == 0) {
        store_cg(h0u + (size_t)((t + 1) & 1) * 262144 + off, hv);
        if (t < SEQ - 1) store_cg(h0m + (size_t)((t + 1) & 1) * 262144 + off, hm);
      } else {
        store_cg(h1u + (size_t)(t + 1) * 262144 + off, hv);
        if (t < SEQ - 1) store_cg(h1m + (size_t)((t + 1) & 1) * 262144 + off, hm);
      }
      if (t == SEQ - 1) {
        float* dh = dout + 32768 + (size_t)layer * LSZ + (size_t)rowg * HID + H0;
        float* dc = dout + 32768 + 2 * LSZ + (size_t)layer * LSZ + (size_t)rowg * HID + H0;
        #pragma unroll
        for (int j = 0; j < 8; ++j) { dh[j] = h2a[j]; dc[j] = c2a[j]; }
      }
    }
    wait_vm0();
    __syncthreads();
    if (tid == 0) __hip_atomic_fetch_add(myf, 1, __ATOMIC_RELAXED, __HIP_MEMORY_SCOPE_AGENT);
  }
}

// ---------------- LayerNorm row stats (reads h1u frag layout) ----------------
__global__ void ln_stats(const u16* __restrict__ h1u, float* __restrict__ mu, float* __restrict__ rstd) {
  int R = blockIdx.x * 4 + (threadIdx.x >> 6);
  int l = threadIdx.x & 63;
  int t = R >> 8, brow = R & 255, grt = brow >> 4, rl = brow & 15;
  const u16* base = h1u + (size_t)(t + 1) * 262144 + (size_t)(grt * 32 + (l >> 1)) * 512;
  int q2 = (l & 1) * 2;
  short8 v0 = *(const short8*)(base + (q2 * 16 + rl) * 8);
  short8 v1 = *(const short8*)(base + ((q2 + 1) * 16 + rl) * 8);
  float s = 0.f, q = 0.f;
  #pragma unroll
  for (int e = 0; e < 8; ++e) {
    float a = b2f((u16)v0[e]); s += a; q += a*a;
    float b = b2f((u16)v1[e]); s += b; q += b*b;
  }
  for (int o = 32; o > 0; o >>= 1) { s += __shfl_xor(s, o); q += __shfl_xor(q, o); }
  if (l == 0) {
    float mm = s * (1.f/1024.f);
    float var = q * (1.f/1024.f) - mm*mm;
    mu[R] = mm; rstd[R] = rsqrtf(var + 1e-5f);
  }
}

// ---------------- MLP GEMM: 128x128 tile, amode1 = A in h1u frag layout ----------------
__global__ __launch_bounds__(512, 4) void mlp_gemm(
    const u16* __restrict__ A, int lda, int amode,
    const u16* __restrict__ B, int K, int N,
    u16* __restrict__ out, int ldo, int mode, int swiz,
    const float* __restrict__ mu, const float* __restrict__ rstd,
    const float* __restrict__ S1v, const float* __restrict__ bias)
{
  int nt, mtb;
  if (swiz) { int p = blockIdx.x * gridDim.y + blockIdx.y; nt = p & 3; mtb = p >> 2; }
  else { nt = blockIdx.x; mtb = blockIdx.y; }
  const int tid = threadIdx.x, lane = tid & 63, wv = tid >> 6;
  const int quad = lane >> 4, c16 = lane & 15;
  __shared__ __align__(16) u16 Am[16384], Bm[16384];
  f32x4 acc[8];
  #pragma unroll
  for (int i = 0; i < 8; ++i) acc[i] = (f32x4){0.f,0.f,0.f,0.f};

  int arow[4], akl[4], bcol[4];
  #pragma unroll
  for (int i = 0; i < 4; ++i) {
    int s = tid + i * 512, sub = s >> 6, lp = s & 63;
    int ks = sub >> 3, u = sub & 7;
    arow[i] = mtb * 128 + u * 16 + (lp & 15);
    akl[i]  = ks * 32 + (lp >> 4) * 8;
    bcol[i] = nt * 128 + u * 16 + (lp & 15);
  }
  short8 vA[4], vB[4];
  const short8 z8 = {0,0,0,0,0,0,0,0};
  const int NCH = K >> 7;
  auto load_stage = [&](int ci) {
    int kc = ci << 7;
    #pragma unroll
    for (int i = 0; i < 4; ++i) {
      if (amode) {
        int R = arow[i], k = kc + akl[i];
        const u16* p = A + (size_t)((R >> 8) + 1) * 262144
                         + (size_t)(((R >> 4) & 15) * 32 + (k >> 5)) * 512
                         + (size_t)((((k >> 3) & 3) * 16 + (R & 15)) * 8);
        vA[i] = *(const short8*)p;
      } else {
        vA[i] = *(const short8*)(A + (size_t)arow[i] * lda + kc + akl[i]);
      }
      vB[i] = (bcol[i] < N) ? *(const short8*)(B + (size_t)bcol[i] * K + kc + akl[i]) : z8;
    }
  };
  load_stage(0);
  for (int ci = 0; ci < NCH; ++ci) {
    #pragma unroll
    for (int i = 0; i < 4; ++i) {
      *(short8*)&Am[(size_t)(tid + i*512) * 8] = vA[i];
      *(short8*)&Bm[(size_t)(tid + i*512) * 8] = vB[i];
    }
    __syncthreads();
    if (ci + 1 < NCH) load_stage(ci + 1);
    #pragma unroll
    for (int ks = 0; ks < 4; ++ks) {
      short8 bf = *(const short8*)&Bm[((ks*8 + wv)*64 + lane) * 8];
      #pragma unroll
      for (int rt = 0; rt < 8; ++rt) {
        short8 af = *(const short8*)&Am[((ks*8 + rt)*64 + lane) * 8];
        acc[rt] = MFMA(af, bf, acc[rt]);
      }
    }
    __syncthreads();
  }
  int col = nt * 128 + wv * 16 + c16;
  if (col < N) {
    #pragma unroll
    for (int rt = 0; rt < 8; ++rt) {
      #pragma unroll
      for (int rgi = 0; rgi < 4; ++rgi) {
        int row = mtb * 128 + rt * 16 + quad * 4 + rgi;
        float v = acc[rt][rgi];
        if (mode == 0) v = v * rstd[row] - mu[row] * rstd[row] * S1v[col] + bias[col];
        else           v = v + bias[col];
        v = eluf(v);
        out[(size_t)row * ldo + col] = f2b(v);
      }
    }
  }
}

__global__ void value_head(const u16* __restrict__ a3, const float* __restrict__ wv,
                           const float* __restrict__ bv, float* __restrict__ dout) {
  int row = blockIdx.x * 256 + threadIdx.x;
  const short8* p = (const short8*)(a3 + (size_t)row * 64);
  float s = bv[0];
  #pragma unroll
  for (int j = 0; j < 8; ++j) {
    short8 v = p[j];
    #pragma unroll
    for (int e = 0; e < 8; ++e) s += b2f((u16)v[e]) * wv[j*8+e];
  }
  dout[row] = s;
}

extern "C" void kernel_launch(void* const* d_in, const int* in_sizes, int n_in,
                              void* d_out, int out_size, void* d_ws, size_t ws_size,
                              hipStream_t stream) {
  (void)in_sizes; (void)n_in; (void)out_size; (void)ws_size;
  const float* x    = (const float*)d_in[0];
  const int*   done = (const int*)d_in[1];
  const float* h0in = (const float*)d_in[2];
  const float* c0in = (const float*)d_in[3];
  const float* wih0 = (const float*)d_in[4];
  const float* whh0 = (const float*)d_in[5];
  const float* bih0 = (const float*)d_in[6];
  const float* bhh0 = (const float*)d_in[7];
  const float* wih1 = (const float*)d_in[8];
  const float* whh1 = (const float*)d_in[9];
  const float* bih1 = (const float*)d_in[10];
  const float* bhh1 = (const float*)d_in[11];
  const float* lng  = (const float*)d_in[12];
  const float* lnb  = (const float*)d_in[13];
  const float* w1   = (const float*)d_in[14];
  const float* b1   = (const float*)d_in[15];
  const float* w2   = (const float*)d_in[16];
  const float* b2   = (const float*)d_in[17];
  const float* w3   = (const float*)d_in[18];
  const float* b3   = (const float*)d_in[19];
  const float* wvp  = (const float*)d_in[20];
  const float* bvp  = (const float*)d_in[21];
  float* dout = (float*)d_out;
  char* ws = (char*)d_ws;

  u16*   w0f  = (u16*)(ws + OFF_W0F);
  u16*   w1f  = (u16*)(ws + OFF_W1F);
  u16*   xf   = (u16*)(ws + OFF_XF);
  u16*   h0u  = (u16*)(ws + OFF_H0U);
  u16*   h1u  = (u16*)(ws + OFF_H1U);
  u16*   h0m  = (u16*)(ws + OFF_H0M);
  u16*   h1m  = (u16*)(ws + OFF_H1M);
  float* c0b  = (float*)(ws + OFF_C0);
  float* c1b  = (float*)(ws + OFF_C1);
  float* bs0  = (float*)(ws + OFF_BS0);
  float* bs1  = (float*)(ws + OFF_BS1);
  int*   flg  = (int*)(ws + OFF_FLG);
  float* mu   = (float*)(ws + OFF_MU);
  float* rstd = (float*)(ws + OFF_RSTD);
  u16*   w1ln = (u16*)(ws + OFF_W1LN);
  float* s1   = (float*)(ws + OFF_S1);
  float* b1p  = (float*)(ws + OFF_B1P);
  u16*   w2b  = (u16*)(ws + OFF_W2B);
  u16*   w3b  = (u16*)(ws + OFF_W3B);
  u16*   a1   = (u16*)(ws + OFF_A1);
  u16*   a2   = (u16*)(ws + OFF_A2);
  u16*   a3   = (u16*)(ws + OFF_A3);

  prep_wf<<<256, 256, 0, stream>>>(wih0, whh0, w0f, 34, 64);
  prep_wf<<<256, 256, 0, stream>>>(wih1, whh1, w1f, 64, 1024);
  prep_w1ln<<<512, 256, 0, stream>>>(w1, lng, lnb, b1, w1ln, s1, b1p);
  prep_misc<<<12609, 256, 0, stream>>>(bih0, bhh0, bih1, bhh1, x, h0in, c0in, w2, w3, done,
                                       bs0, bs1, xf, h0m, h1m, c0b, c1b, w2b, w3b, flg);

  lstm_persist<<<256, 256, 0, stream>>>(w0f, w1f, xf, h0u, h1u, h0m, h1m, c0b, c1b,
                                        bs0, bs1, done, flg, dout);

  ln_stats<<<8192, 256, 0, stream>>>(h1u, mu, rstd);
  mlp_gemm<<<dim3(8, 128), 512, 0, stream>>>(h1u, 0, 1, w1ln, 1024, 512, a1, 512, 0, 1, mu, rstd, s1, b1p);
  mlp_gemm<<<dim3(1, 256), 512, 0, stream>>>(a1, 512, 0, w2b, 512, 128, a2, 128, 1, 0, mu, rstd, s1, b2);
  mlp_gemm<<<dim3(1, 256), 512, 0, stream>>>(a2, 128, 0, w3b, 128, 64, a3, 64, 1, 0, mu, rstd, s1, b3);
  value_head<<<128, 256, 0, stream>>>(a3, wvp, bvp, dout);
}

// Round 5
// 2741.826 us; speedup vs baseline: 1.1264x; 1.1264x over previous
//
#include <hip/hip_runtime.h>
#include <cstdint>
#include <cstddef>

typedef unsigned short u16;
typedef __attribute__((ext_vector_type(8))) short short8;
typedef __attribute__((ext_vector_type(4))) float f32x4;

#define SEQ 128
#define BATCH 256
#define HID 1024
#define LSZ 262144

#define MFMA(a,b,c) __builtin_amdgcn_mfma_f32_16x16x32_bf16((a),(b),(c),0,0,0)

// global -> LDS direct (16B/lane, wave-uniform LDS base + lane*16).
// aux 17 = sc0|sc1 (system-coherent, bypass stale L2); aux 0 = cached.
#define GLDS_CG(g, l) __builtin_amdgcn_global_load_lds( \
  (__attribute__((address_space(1))) void*)(uintptr_t)(const void*)(g), \
  (__attribute__((address_space(3))) void*)(unsigned)(uintptr_t)(void*)(l), 16, 0, 17)
#define GLDS_NC(g, l) __builtin_amdgcn_global_load_lds( \
  (__attribute__((address_space(1))) void*)(uintptr_t)(const void*)(g), \
  (__attribute__((address_space(3))) void*)(unsigned)(uintptr_t)(void*)(l), 16, 0, 0)

__device__ __forceinline__ u16 f2b(float f) {
  union { float f; unsigned u; } v; v.f = f;
  unsigned r = (v.u + 0x7FFFu + ((v.u >> 16) & 1u)) >> 16;
  return (u16)r;
}
__device__ __forceinline__ float b2f(u16 h) {
  union { unsigned u; float f; } v; v.u = ((unsigned)h) << 16; return v.f;
}
__device__ __forceinline__ float sigm(float x){ return 1.f/(1.f + __expf(-x)); }
__device__ __forceinline__ float tanh_f(float x){
  x = fminf(15.f, fmaxf(-15.f, x));
  float e = __expf(2.f*x); return (e-1.f)/(e+1.f);
}
__device__ __forceinline__ float eluf(float x){ return x > 0.f ? x : expm1f(x); }

__device__ __forceinline__ void store_cg(u16* p, short8 v) {
  asm volatile("global_store_dwordx4 %0, %1, off sc0 sc1" :: "v"(p), "v"(v) : "memory");
}
__device__ __forceinline__ void wait_vm0() {
  asm volatile("s_waitcnt vmcnt(0)" ::: "memory");
}
__device__ __forceinline__ void waitgroup(int* f, int tgt) {
  if (threadIdx.x < 64) {
    int idx = threadIdx.x & 31;
    while (__hip_atomic_load(f + idx, __ATOMIC_RELAXED, __HIP_MEMORY_SCOPE_AGENT) < tgt)
      __builtin_amdgcn_s_sleep(1);
  }
  __syncthreads();
}

// ---------------- workspace layout (bytes) ----------------
static const size_t OFF_W0F  = 0;           // 32cg*34kb*8ct*512*2 = 8912896
static const size_t OFF_W1F  = 8912896;     // 32*64*8*512*2 = 16777216
static const size_t OFF_XF   = 25690112;    // 128t*16grt*2kb*512*2 = 4194304
static const size_t OFF_H0U  = 29884416;    // 2 slots * 524288 (UNMASKED h0, for L1 input)
static const size_t OFF_C0   = 30932992;    // fp32 256x1024
static const size_t OFF_C1   = 31981568;
static const size_t OFF_H1U  = 33030144;    // 129 slots * 524288 (slot t+1 == hs[t], unmasked)
static const size_t OFF_BS0  = 100663296;
static const size_t OFF_BS1  = 100679680;
static const size_t OFF_MU   = 100697088;   // ALSO hosts 512 lstm flags (dead before ln_stats)
static const size_t OFF_RSTD = 100828160;
static const size_t OFF_W1LN = 100959232;
static const size_t OFF_S1   = 102007808;
static const size_t OFF_B1P  = 102009856;
static const size_t OFF_W2B  = 102011904;
static const size_t OFF_W3B  = 102142976;
static const size_t OFF_A1   = 102159360;   // 33554432 -> end 135713792
static const size_t OFF_A2   = 0;           // alias dead w0f (post-lstm)
static const size_t OFF_A3   = 8912896;     // alias dead w1f (post-lstm)
// masked-h rings alias the A1 region (A1 written only after lstm completes)
static const size_t OFF_H0M  = 102159360;            // 2 slots * 524288
static const size_t OFF_H1M  = 102159360 + 1048576;  // 2 slots * 524288

// ---------------- prep: weights into fragment-linear tiles ----------------
__global__ void prep_wf(const float* __restrict__ wih, const float* __restrict__ whh,
                        u16* __restrict__ out, int nkb, int kx) {
  int b = blockIdx.x; int cg = b >> 3, ct = b & 7;
  int g = ct >> 1;
  int n = nkb << 9;
  for (int e = threadIdx.x; e < n; e += 256) {
    int kb = e >> 9, r = e & 511;
    int q = r >> 7, col16 = (r >> 3) & 15, j = r & 7;
    int hl = (ct & 1) * 16 + col16;
    int gr = g * HID + cg * 32 + hl;
    int k = kb * 32 + q * 8 + j;
    float w = (k < kx) ? wih[(size_t)gr * kx + k] : whh[(size_t)gr * HID + (k - kx)];
    out[((size_t)(cg * nkb + kb) * 8 + ct) * 512 + r] = f2b(w);
  }
}

__global__ void prep_w1ln(const float* __restrict__ w1, const float* __restrict__ lng,
                          const float* __restrict__ lnb, const float* __restrict__ b1,
                          u16* __restrict__ w1ln, float* __restrict__ S1, float* __restrict__ b1p) {
  int j = blockIdx.x;
  float s = 0.f, bb = 0.f;
  for (int k = threadIdx.x; k < HID; k += 256) {
    float w = w1[(size_t)j * HID + k];
    u16 q = f2b(w * lng[k]);
    w1ln[(size_t)j * HID + k] = q;
    s += b2f(q);
    bb += w * lnb[k];
  }
  __shared__ float r1[256], r2[256];
  r1[threadIdx.x] = s; r2[threadIdx.x] = bb;
  __syncthreads();
  for (int o = 128; o > 0; o >>= 1) {
    if (threadIdx.x < (unsigned)o) { r1[threadIdx.x] += r1[threadIdx.x+o]; r2[threadIdx.x] += r2[threadIdx.x+o]; }
    __syncthreads();
  }
  if (threadIdx.x == 0) { S1[j] = r1[0]; b1p[j] = b1[j] + r2[0]; }
}

__global__ void prep_misc(const float* bih0, const float* bhh0, const float* bih1, const float* bhh1,
                          const float* x, const float* h0in, const float* c0in,
                          const float* w2, const float* w3, const int* done,
                          float* bs0, float* bs1, u16* xf, u16* h0m, u16* h1m,
                          float* c0buf, float* c1buf, u16* w2b, u16* w3b, int* flg) {
  size_t i = (size_t)blockIdx.x * blockDim.x + threadIdx.x;
  if (i < 4096) { bs0[i] = bih0[i] + bhh0[i]; return; }
  i -= 4096;
  if (i < 4096) { bs1[i] = bih1[i] + bhh1[i]; return; }
  i -= 4096;
  if (i < 2097152) {
    int o = (int)i;
    int r = o & 511, tile = o >> 9;
    int q = r >> 7, rl = (r >> 3) & 15, j = r & 7;
    int kb = tile & 1, v = tile >> 1;
    int grt = v & 15, t = v >> 4;
    int row = grt * 16 + rl, k = kb * 32 + q * 8 + j;
    xf[o] = f2b(x[((size_t)t * BATCH + row) * 64 + k]);
    return;
  }
  i -= 2097152;
  if (i < 262144) {   // h0m slot 0: MASKED initial h0 (layer0 recurrent input @ t=0)
    int o = (int)i;
    int r = o & 511, tile = o >> 9;
    int q = r >> 7, rl = (r >> 3) & 15, j = r & 7;
    int grt = tile >> 5, kb = tile & 31;
    int row = grt * 16 + rl, h = kb * 32 + q * 8 + j;
    h0m[o] = done[row] ? (u16)0 : f2b(h0in[(size_t)row * HID + h]);
    return;
  }
  i -= 262144;
  if (i < 262144) {   // h1m slot 0: MASKED initial h1 (layer1 recurrent input @ t=0)
    int o = (int)i;
    int r = o & 511, tile = o >> 9;
    int q = r >> 7, rl = (r >> 3) & 15, j = r & 7;
    int grt = tile >> 5, kb = tile & 31;
    int row = grt * 16 + rl, h = kb * 32 + q * 8 + j;
    h1m[o] = done[row] ? (u16)0 : f2b(h0in[LSZ + (size_t)row * HID + h]);
    return;
  }
  i -= 262144;
  if (i < LSZ) { c0buf[i] = c0in[i]; return; }
  i -= LSZ;
  if (i < LSZ) { c1buf[i] = c0in[LSZ + i]; return; }
  i -= LSZ;
  if (i < 65536) { w2b[i] = f2b(w2[i]); return; }
  i -= 65536;
  if (i < 8192) { w3b[i] = f2b(w3[i]); return; }
  i -= 8192;
  if (i < 512) { flg[i] = 0; return; }
}

// ---------------- persistent LSTM recurrence ----------------
// 512 blocks x 256 thr -> 2 blocks/CU (TLP: co-resident blocks anti-phase).
// bid = layer*256 + rg*32 + cg; rg 0..7 (32-row group), cg 0..31 (32 h-cols).
// block tile 32 rows x 128 gate-cols; wave wv owns 32-col slice (B dedup'd).
// Pipeline position p -> chunk ocmap(p): L0 identity; L1 h1-part first, L0-flag
// wait at position 6. A: global_load_lds, 4 bufs, depth 2. B: reg loads, depth 2.
// One static s_waitcnt vmcnt(20) + s_barrier per chunk.
__global__ __launch_bounds__(256, 2) void lstm_persist(
    const u16* __restrict__ w0f, const u16* __restrict__ w1f, const u16* __restrict__ xf,
    u16* __restrict__ h0u, u16* __restrict__ h1u,
    u16* __restrict__ h0m, u16* __restrict__ h1m,
    float* __restrict__ c0b, float* __restrict__ c1b,
    const float* __restrict__ bs0, const float* __restrict__ bs1,
    const int* __restrict__ done, int* __restrict__ flg,
    float* __restrict__ dout)
{
  const int bid = blockIdx.x;
  const int layer = bid >> 8;
  const int rg = (bid >> 5) & 7;
  const int cg = bid & 31;
  const int tid = threadIdx.x;
  const int lane = tid & 63, wv = tid >> 6;
  const int quad = lane >> 4, c16 = lane & 15;
  const int NKB = layer ? 64 : 34;
  const int NC  = layer ? 16 : 9;
  const u16* Wf = layer ? w1f : w0f;
  const float* bs = layer ? bs1 : bs0;
  float* cb = layer ? c1b : c0b;
  int* fl0 = flg;
  int* fl1 = flg + 256;
  int* myf = (layer ? fl1 : fl0) + rg * 32 + cg;
  int* g0 = fl0 + rg * 32;
  int* g1 = fl1 + rg * 32;

  __shared__ __align__(16) u16 smem[16384];  // 4 x 8KB A buffers; epilogue gl aliases
  float* gl = (float*)smem;                  // 32 x 132 fp32 (padded stride)

  const short8 z8 = {0,0,0,0,0,0,0,0};

  for (int t = 0; t < SEQ; ++t) {
    // step-top: cheap same-group (sibling) waits
    if (layer == 0) {
      if (t >= 1) waitgroup(g0, t);        // siblings' h0m(t-1) ready
    } else {
      if (t >= 1) waitgroup(g1, t);        // siblings' h1m(t-1) ready (also WAR)
    }

    auto ocmap = [&](int p) -> int {
      if (layer) return p >= 16 ? 7 : (p < 8 ? p + 8 : p - 8);
      return p > 8 ? 8 : p;
    };

    // A chunk: kb in [oc*4, oc*4+4); wave wv stages kbl=wv, 2 grt tiles (j=0,1).
    // LDS buf (p&3): tile (kbl,j) at u16 offset (kbl*2+j)*512.
    auto issueA = [&](int p) {
      int oc = ocmap(p);
      int kb = oc * 4 + wv; if (kb > NKB - 1) kb = NKB - 1;
      u16* lb = &smem[((unsigned)(p & 3)) * 4096 + (unsigned)wv * 1024];
      if (layer == 0) {
        if (kb < 2) {
          #pragma unroll
          for (int j = 0; j < 2; ++j) {
            const u16* g = xf + ((size_t)((t * 16 + rg * 2 + j) * 2 + kb)) * 512 + lane * 8;
            GLDS_NC(g, lb + j * 512);
          }
        } else {
          #pragma unroll
          for (int j = 0; j < 2; ++j) {
            const u16* g = h0m + (size_t)(t & 1) * 262144
                               + (size_t)((rg * 2 + j) * 32 + (kb - 2)) * 512 + lane * 8;
            GLDS_CG(g, lb + j * 512);
          }
        }
      } else {
        if (kb < 32) {
          #pragma unroll
          for (int j = 0; j < 2; ++j) {
            const u16* g = h0u + (size_t)((t + 1) & 1) * 262144
                               + (size_t)((rg * 2 + j) * 32 + kb) * 512 + lane * 8;
            GLDS_CG(g, lb + j * 512);
          }
        } else {
          #pragma unroll
          for (int j = 0; j < 2; ++j) {
            const u16* g = h1m + (size_t)(t & 1) * 262144
                               + (size_t)((rg * 2 + j) * 32 + (kb - 32)) * 512 + lane * 8;
            GLDS_CG(g, lb + j * 512);
          }
        }
      }
    };

    auto loadB = [&](int p, short8 (&vB)[4][2]) {
      int oc = ocmap(p);
      #pragma unroll
      for (int kbl = 0; kbl < 4; ++kbl) {
        int kb = oc * 4 + kbl; if (kb > NKB - 1) kb = NKB - 1;
        #pragma unroll
        for (int h = 0; h < 2; ++h)
          vB[kbl][h] = *(const short8*)(Wf + ((size_t)(cg * NKB + kb) * 8 + wv * 2 + h) * 512 + lane * 8);
      }
    };

    f32x4 acc[2][2];
    #pragma unroll
    for (int a = 0; a < 2; ++a) { acc[a][0] = (f32x4){0,0,0,0}; acc[a][1] = (f32x4){0,0,0,0}; }

    auto comp = [&](int p, short8 (&vB)[4][2]) {
      int oc = ocmap(p);
      int kbc = NKB - oc * 4; if (kbc > 4) kbc = 4;
      const u16* sb = &smem[((unsigned)(p & 3)) * 4096] + lane * 8;
      #pragma unroll
      for (int kbl = 0; kbl < 4; ++kbl) if (kbl < kbc) {
        #pragma unroll
        for (int a = 0; a < 2; ++a) {
          short8 af = *(const short8*)(sb + (kbl * 2 + a) * 512);
          acc[a][0] = MFMA(af, vB[kbl][0], acc[a][0]);
          acc[a][1] = MFMA(af, vB[kbl][1], acc[a][1]);
        }
      }
    };

    short8 vB0[4][2], vB1[4][2], vB2[4][2];

    // prologue: positions 0,1 (L1: oc 8,9 = own h1 recurrence -> no L0 dep)
    loadB(0, vB0); issueA(0);
    asm volatile("" ::: "memory");
    loadB(1, vB1); issueA(1);

    // steady state: 2 segments (20 loads) in flight across the wait.
#define CHUNK(CC, VBL, VBU) \
    if (layer && (CC) == 6) waitgroup(g0, t + 1); \
    loadB((CC) + 2, VBL); issueA((CC) + 2); \
    asm volatile("s_waitcnt vmcnt(20)" ::: "memory"); \
    __builtin_amdgcn_s_barrier(); \
    __builtin_amdgcn_sched_barrier(0); \
    comp((CC), VBU);

    int c = 0;
    for (;;) {
      CHUNK(c, vB2, vB0) if (++c == NC) break;
      CHUNK(c, vB0, vB1) if (++c == NC) break;
      CHUNK(c, vB1, vB2) if (++c == NC) break;
    }
#undef CHUNK

    // drain dummy prefetches before aliasing smem as gl; sync all waves' comp
    wait_vm0();
    __syncthreads();

    // epilogue: gates -> LDS gl[row32][132]; wave wv owns cols [wv*32, wv*32+32)
    #pragma unroll
    for (int a = 0; a < 2; ++a)
      #pragma unroll
      for (int ct = 0; ct < 2; ++ct)
        #pragma unroll
        for (int rgi = 0; rgi < 4; ++rgi)
          gl[(a * 16 + quad * 4 + rgi) * 132 + wv * 32 + ct * 16 + c16] = acc[a][ct][rgi];
    __syncthreads();

    // L0's WAR wait (guards only the h0u/h0m stores below)
    if (layer == 0 && t >= 2) waitgroup(g1, t - 1);

    if (tid < 128) {
      int row = tid >> 2;           // 0..31
      int q = tid & 3;
      int h8 = q * 8;
      int rowg = rg * 32 + row;
      int H0 = cg * 32 + h8;
      const float* glp = gl + row * 132;
      float m = done[t * BATCH + rowg] ? 0.f : 1.f;
      int nx = (t < SEQ - 1) ? done[(t + 1) * BATCH + rowg] : 0;
      float* cp = cb + (size_t)rowg * HID + H0;
      short8 hv;
      float h2a[8], c2a[8];
      #pragma unroll
      for (int j = 0; j < 8; ++j) {
        float ivv = glp[h8 + j]      + bs[H0 + j];
        float fvv = glp[32 + h8 + j] + bs[HID + H0 + j];
        float gvv = glp[64 + h8 + j] + bs[2*HID + H0 + j];
        float ovv = glp[96 + h8 + j] + bs[3*HID + H0 + j];
        float c2 = sigm(fvv) * (cp[j] * m) + sigm(ivv) * tanh_f(gvv);
        float h2 = sigm(ovv) * tanh_f(c2);
        cp[j] = c2;
        h2a[j] = h2; c2a[j] = c2;
        ((u16*)&hv)[j] = f2b(h2);
      }
      short8 hm = nx ? z8 : hv;
      size_t off = (size_t)((rg * 2 + (row >> 4)) * 32 + cg) * 512 + (size_t)(q * 16 + (row & 15)) * 8;
      if (layer == 0) {
        store_cg(h0u + (size_t)((t + 1) & 1) * 262144 + off, hv);
        if (t < SEQ - 1) store_cg(h0m + (size_t)((t + 1) & 1) * 262144 + off, hm);
      } else {
        store_cg(h1u + (size_t)(t + 1) * 262144 + off, hv);
        if (t < SEQ - 1) store_cg(h1m + (size_t)((t + 1) & 1) * 262144 + off, hm);
      }
      if (t == SEQ - 1) {
        float* dh = dout + 32768 + (size_t)layer * LSZ + (size_t)rowg * HID + H0;
        float* dc = dout + 32768 + 2 * LSZ + (size_t)layer * LSZ + (size_t)rowg * HID + H0;
        #pragma unroll
        for (int j = 0; j < 8; ++j) { dh[j] = h2a[j]; dc[j] = c2a[j]; }
      }
    }
    wait_vm0();
    __syncthreads();
    if (tid == 0) __hip_atomic_fetch_add(myf, 1, __ATOMIC_RELAXED, __HIP_MEMORY_SCOPE_AGENT);
  }
}

// ---------------- LayerNorm row stats (reads h1u frag layout) ----------------
__global__ void ln_stats(const u16* __restrict__ h1u, float* __restrict__ mu, float* __restrict__ rstd) {
  int R = blockIdx.x * 4 + (threadIdx.x >> 6);
  int l = threadIdx.x & 63;
  int t = R >> 8, brow = R & 255, grt = brow >> 4, rl = brow & 15;
  const u16* base = h1u + (size_t)(t + 1) * 262144 + (size_t)(grt * 32 + (l >> 1)) * 512;
  int q2 = (l & 1) * 2;
  short8 v0 = *(const short8*)(base + (q2 * 16 + rl) * 8);
  short8 v1 = *(const short8*)(base + ((q2 + 1) * 16 + rl) * 8);
  float s = 0.f, q = 0.f;
  #pragma unroll
  for (int e = 0; e < 8; ++e) {
    float a = b2f((u16)v0[e]); s += a; q += a*a;
    float b = b2f((u16)v1[e]); s += b; q += b*b;
  }
  for (int o = 32; o > 0; o >>= 1) { s += __shfl_xor(s, o); q += __shfl_xor(q, o); }
  if (l == 0) {
    float mm = s * (1.f/1024.f);
    float var = q * (1.f/1024.f) - mm*mm;
    mu[R] = mm; rstd[R] = rsqrtf(var + 1e-5f);
  }
}

// ---------------- MLP GEMM: 128x128 tile, amode1 = A in h1u frag layout ----------------
__global__ __launch_bounds__(512, 4) void mlp_gemm(
    const u16* __restrict__ A, int lda, int amode,
    const u16* __restrict__ B, int K, int N,
    u16* __restrict__ out, int ldo, int mode, int swiz,
    const float* __restrict__ mu, const float* __restrict__ rstd,
    const float* __restrict__ S1v, const float* __restrict__ bias)
{
  int nt, mtb;
  if (swiz) { int p = blockIdx.x * gridDim.y + blockIdx.y; nt = p & 3; mtb = p >> 2; }
  else { nt = blockIdx.x; mtb = blockIdx.y; }
  const int tid = threadIdx.x, lane = tid & 63, wv = tid >> 6;
  const int quad = lane >> 4, c16 = lane & 15;
  __shared__ __align__(16) u16 Am[16384], Bm[16384];
  f32x4 acc[8];
  #pragma unroll
  for (int i = 0; i < 8; ++i) acc[i] = (f32x4){0.f,0.f,0.f,0.f};

  int arow[4], akl[4], bcol[4];
  #pragma unroll
  for (int i = 0; i < 4; ++i) {
    int s = tid + i * 512, sub = s >> 6, lp = s & 63;
    int ks = sub >> 3, u = sub & 7;
    arow[i] = mtb * 128 + u * 16 + (lp & 15);
    akl[i]  = ks * 32 + (lp >> 4) * 8;
    bcol[i] = nt * 128 + u * 16 + (lp & 15);
  }
  short8 vA[4], vB[4];
  const short8 z8 = {0,0,0,0,0,0,0,0};
  const int NCH = K >> 7;
  auto load_stage = [&](int ci) {
    int kc = ci << 7;
    #pragma unroll
    for (int i = 0; i < 4; ++i) {
      if (amode) {
        int R = arow[i], k = kc + akl[i];
        const u16* p = A + (size_t)((R >> 8) + 1) * 262144
                         + (size_t)(((R >> 4) & 15) * 32 + (k >> 5)) * 512
                         + (size_t)((((k >> 3) & 3) * 16 + (R & 15)) * 8);
        vA[i] = *(const short8*)p;
      } else {
        vA[i] = *(const short8*)(A + (size_t)arow[i] * lda + kc + akl[i]);
      }
      vB[i] = (bcol[i] < N) ? *(const short8*)(B + (size_t)bcol[i] * K + kc + akl[i]) : z8;
    }
  };
  load_stage(0);
  for (int ci = 0; ci < NCH; ++ci) {
    #pragma unroll
    for (int i = 0; i < 4; ++i) {
      *(short8*)&Am[(size_t)(tid + i*512) * 8] = vA[i];
      *(short8*)&Bm[(size_t)(tid + i*512) * 8] = vB[i];
    }
    __syncthreads();
    if (ci + 1 < NCH) load_stage(ci + 1);
    #pragma unroll
    for (int ks = 0; ks < 4; ++ks) {
      short8 bf = *(const short8*)&Bm[((ks*8 + wv)*64 + lane) * 8];
      #pragma unroll
      for (int rt = 0; rt < 8; ++rt) {
        short8 af = *(const short8*)&Am[((ks*8 + rt)*64 + lane) * 8];
        acc[rt] = MFMA(af, bf, acc[rt]);
      }
    }
    __syncthreads();
  }
  int col = nt * 128 + wv * 16 + c16;
  if (col < N) {
    #pragma unroll
    for (int rt = 0; rt < 8; ++rt) {
      #pragma unroll
      for (int rgi = 0; rgi < 4; ++rgi) {
        int row = mtb * 128 + rt * 16 + quad * 4 + rgi;
        float v = acc[rt][rgi];
        if (mode == 0) v = v * rstd[row] - mu[row] * rstd[row] * S1v[col] + bias[col];
        else           v = v + bias[col];
        v = eluf(v);
        out[(size_t)row * ldo + col] = f2b(v);
      }
    }
  }
}

__global__ void value_head(const u16* __restrict__ a3, const float* __restrict__ wv,
                           const float* __restrict__ bv, float* __restrict__ dout) {
  int row = blockIdx.x * 256 + threadIdx.x;
  const short8* p = (const short8*)(a3 + (size_t)row * 64);
  float s = bv[0];
  #pragma unroll
  for (int j = 0; j < 8; ++j) {
    short8 v = p[j];
    #pragma unroll
    for (int e = 0; e < 8; ++e) s += b2f((u16)v[e]) * wv[j*8+e];
  }
  dout[row] = s;
}

extern "C" void kernel_launch(void* const* d_in, const int* in_sizes, int n_in,
                              void* d_out, int out_size, void* d_ws, size_t ws_size,
                              hipStream_t stream) {
  (void)in_sizes; (void)n_in; (void)out_size; (void)ws_size;
  const float* x    = (const float*)d_in[0];
  const int*   done = (const int*)d_in[1];
  const float* h0in = (const float*)d_in[2];
  const float* c0in = (const float*)d_in[3];
  const float* wih0 = (const float*)d_in[4];
  const float* whh0 = (const float*)d_in[5];
  const float* bih0 = (const float*)d_in[6];
  const float* bhh0 = (const float*)d_in[7];
  const float* wih1 = (const float*)d_in[8];
  const float* whh1 = (const float*)d_in[9];
  const float* bih1 = (const float*)d_in[10];
  const float* bhh1 = (const float*)d_in[11];
  const float* lng  = (const float*)d_in[12];
  const float* lnb  = (const float*)d_in[13];
  const float* w1   = (const float*)d_in[14];
  const float* b1   = (const float*)d_in[15];
  const float* w2   = (const float*)d_in[16];
  const float* b2   = (const float*)d_in[17];
  const float* w3   = (const float*)d_in[18];
  const float* b3   = (const float*)d_in[19];
  const float* wvp  = (const float*)d_in[20];
  const float* bvp  = (const float*)d_in[21];
  float* dout = (float*)d_out;
  char* ws = (char*)d_ws;

  u16*   w0f  = (u16*)(ws + OFF_W0F);
  u16*   w1f  = (u16*)(ws + OFF_W1F);
  u16*   xf   = (u16*)(ws + OFF_XF);
  u16*   h0u  = (u16*)(ws + OFF_H0U);
  u16*   h1u  = (u16*)(ws + OFF_H1U);
  u16*   h0m  = (u16*)(ws + OFF_H0M);
  u16*   h1m  = (u16*)(ws + OFF_H1M);
  float* c0b  = (float*)(ws + OFF_C0);
  float* c1b  = (float*)(ws + OFF_C1);
  float* bs0  = (float*)(ws + OFF_BS0);
  float* bs1  = (float*)(ws + OFF_BS1);
  int*   flg  = (int*)(ws + OFF_MU);   // 512 flags; dead before ln_stats overwrites mu
  float* mu   = (float*)(ws + OFF_MU);
  float* rstd = (float*)(ws + OFF_RSTD);
  u16*   w1ln = (u16*)(ws + OFF_W1LN);
  float* s1   = (float*)(ws + OFF_S1);
  float* b1p  = (float*)(ws + OFF_B1P);
  u16*   w2b  = (u16*)(ws + OFF_W2B);
  u16*   w3b  = (u16*)(ws + OFF_W3B);
  u16*   a1   = (u16*)(ws + OFF_A1);
  u16*   a2   = (u16*)(ws + OFF_A2);
  u16*   a3   = (u16*)(ws + OFF_A3);

  prep_wf<<<256, 256, 0, stream>>>(wih0, whh0, w0f, 34, 64);
  prep_wf<<<256, 256, 0, stream>>>(wih1, whh1, w1f, 64, 1024);
  prep_w1ln<<<512, 256, 0, stream>>>(w1, lng, lnb, b1, w1ln, s1, b1p);
  prep_misc<<<12610, 256, 0, stream>>>(bih0, bhh0, bih1, bhh1, x, h0in, c0in, w2, w3, done,
                                       bs0, bs1, xf, h0m, h1m, c0b, c1b, w2b, w3b, flg);

  lstm_persist<<<512, 256, 0, stream>>>(w0f, w1f, xf, h0u, h1u, h0m, h1m, c0b, c1b,
                                        bs0, bs1, done, flg, dout);

  ln_stats<<<8192, 256, 0, stream>>>(h1u, mu, rstd);
  mlp_gemm<<<dim3(8, 128), 512, 0, stream>>>(h1u, 0, 1, w1ln, 1024, 512, a1, 512, 0, 1, mu, rstd, s1, b1p);
  mlp_gemm<<<dim3(1, 256), 512, 0, stream>>>(a1, 512, 0, w2b, 512, 128, a2, 128, 1, 0, mu, rstd, s1, b2);
  mlp_gemm<<<dim3(1, 256), 512, 0, stream>>>(a2, 128, 0, w3b, 128, 64, a3, 64, 1, 0, mu, rstd, s1, b3);
  value_head<<<128, 256, 0, stream>>>(a3, wvp, bvp, dout);
}

// Round 6
// 2730.240 us; speedup vs baseline: 1.1312x; 1.0042x over previous
//
#include <hip/hip_runtime.h>
#include <cstdint>
#include <cstddef>

typedef unsigned short u16;
typedef __attribute__((ext_vector_type(8))) short short8;
typedef __attribute__((ext_vector_type(4))) float f32x4;

#define SEQ 128
#define BATCH 256
#define HID 1024
#define LSZ 262144

#define MFMA(a,b,c) __builtin_amdgcn_mfma_f32_16x16x32_bf16((a),(b),(c),0,0,0)

// global -> LDS direct (16B/lane, wave-uniform LDS base + lane*16).
// aux 17 = sc0|sc1 (system-coherent, bypass stale L2); aux 0 = cached.
#define GLDS_CG(g, l) __builtin_amdgcn_global_load_lds( \
  (__attribute__((address_space(1))) void*)(uintptr_t)(const void*)(g), \
  (__attribute__((address_space(3))) void*)(unsigned)(uintptr_t)(void*)(l), 16, 0, 17)
#define GLDS_NC(g, l) __builtin_amdgcn_global_load_lds( \
  (__attribute__((address_space(1))) void*)(uintptr_t)(const void*)(g), \
  (__attribute__((address_space(3))) void*)(unsigned)(uintptr_t)(void*)(l), 16, 0, 0)

__device__ __forceinline__ u16 f2b(float f) {
  union { float f; unsigned u; } v; v.f = f;
  unsigned r = (v.u + 0x7FFFu + ((v.u >> 16) & 1u)) >> 16;
  return (u16)r;
}
__device__ __forceinline__ float b2f(u16 h) {
  union { unsigned u; float f; } v; v.u = ((unsigned)h) << 16; return v.f;
}
__device__ __forceinline__ float sigm(float x){ return 1.f/(1.f + __expf(-x)); }
__device__ __forceinline__ float tanh_f(float x){
  x = fminf(15.f, fmaxf(-15.f, x));
  float e = __expf(2.f*x); return (e-1.f)/(e+1.f);
}
__device__ __forceinline__ float eluf(float x){ return x > 0.f ? x : expm1f(x); }

__device__ __forceinline__ void store_cg(u16* p, short8 v) {
  asm volatile("global_store_dwordx4 %0, %1, off sc0 sc1" :: "v"(p), "v"(v) : "memory");
}
__device__ __forceinline__ void wait_vm0() {
  asm volatile("s_waitcnt vmcnt(0)" ::: "memory");
}
// flag wait WITHOUT __syncthreads (raw barrier -> no hidden vmcnt(0) drain)
__device__ __forceinline__ void waitgroup(int* f, int tgt) {
  if (threadIdx.x < 64) {
    int idx = threadIdx.x & 31;
    while (__hip_atomic_load(f + idx, __ATOMIC_RELAXED, __HIP_MEMORY_SCOPE_AGENT) < tgt)
      __builtin_amdgcn_s_sleep(1);
  }
  asm volatile("" ::: "memory");
  __builtin_amdgcn_s_barrier();
  __builtin_amdgcn_sched_barrier(0);
}

// ---------------- workspace layout (bytes) ----------------
static const size_t OFF_W0F  = 0;           // 32cg*34kb*8ct*512*2 = 8912896
static const size_t OFF_W1F  = 8912896;     // 32*64*8*512*2 = 16777216
static const size_t OFF_XF   = 25690112;    // 128t*16grt*2kb*512*2 = 4194304
static const size_t OFF_H0U  = 29884416;    // 2 slots * 524288 (UNMASKED h0, for L1 input)
static const size_t OFF_C0   = 30932992;    // fp32 256x1024
static const size_t OFF_C1   = 31981568;
static const size_t OFF_H1U  = 33030144;    // 129 slots * 524288 (slot t+1 == hs[t], unmasked)
static const size_t OFF_BS0  = 100663296;
static const size_t OFF_BS1  = 100679680;
static const size_t OFF_MU   = 100697088;   // ALSO hosts 512 lstm flags (dead before ln_stats)
static const size_t OFF_RSTD = 100828160;
static const size_t OFF_W1LN = 100959232;
static const size_t OFF_S1   = 102007808;
static const size_t OFF_B1P  = 102009856;
static const size_t OFF_W2B  = 102011904;
static const size_t OFF_W3B  = 102142976;
static const size_t OFF_A1   = 102159360;   // 33554432 -> end 135713792
static const size_t OFF_A2   = 0;           // alias dead w0f (post-lstm)
static const size_t OFF_A3   = 8912896;     // alias dead w1f (post-lstm)
// masked-h rings alias the A1 region (A1 written only after lstm completes)
static const size_t OFF_H0M  = 102159360;            // 2 slots * 524288
static const size_t OFF_H1M  = 102159360 + 1048576;  // 2 slots * 524288

// ---------------- prep: weights into fragment-linear tiles ----------------
__global__ void prep_wf(const float* __restrict__ wih, const float* __restrict__ whh,
                        u16* __restrict__ out, int nkb, int kx) {
  int b = blockIdx.x; int cg = b >> 3, ct = b & 7;
  int g = ct >> 1;
  int n = nkb << 9;
  for (int e = threadIdx.x; e < n; e += 256) {
    int kb = e >> 9, r = e & 511;
    int q = r >> 7, col16 = (r >> 3) & 15, j = r & 7;
    int hl = (ct & 1) * 16 + col16;
    int gr = g * HID + cg * 32 + hl;
    int k = kb * 32 + q * 8 + j;
    float w = (k < kx) ? wih[(size_t)gr * kx + k] : whh[(size_t)gr * HID + (k - kx)];
    out[((size_t)(cg * nkb + kb) * 8 + ct) * 512 + r] = f2b(w);
  }
}

__global__ void prep_w1ln(const float* __restrict__ w1, const float* __restrict__ lng,
                          const float* __restrict__ lnb, const float* __restrict__ b1,
                          u16* __restrict__ w1ln, float* __restrict__ S1, float* __restrict__ b1p) {
  int j = blockIdx.x;
  float s = 0.f, bb = 0.f;
  for (int k = threadIdx.x; k < HID; k += 256) {
    float w = w1[(size_t)j * HID + k];
    u16 q = f2b(w * lng[k]);
    w1ln[(size_t)j * HID + k] = q;
    s += b2f(q);
    bb += w * lnb[k];
  }
  __shared__ float r1[256], r2[256];
  r1[threadIdx.x] = s; r2[threadIdx.x] = bb;
  __syncthreads();
  for (int o = 128; o > 0; o >>= 1) {
    if (threadIdx.x < (unsigned)o) { r1[threadIdx.x] += r1[threadIdx.x+o]; r2[threadIdx.x] += r2[threadIdx.x+o]; }
    __syncthreads();
  }
  if (threadIdx.x == 0) { S1[j] = r1[0]; b1p[j] = b1[j] + r2[0]; }
}

__global__ void prep_misc(const float* bih0, const float* bhh0, const float* bih1, const float* bhh1,
                          const float* x, const float* h0in, const float* c0in,
                          const float* w2, const float* w3, const int* done,
                          float* bs0, float* bs1, u16* xf, u16* h0m, u16* h1m,
                          float* c0buf, float* c1buf, u16* w2b, u16* w3b, int* flg) {
  size_t i = (size_t)blockIdx.x * blockDim.x + threadIdx.x;
  if (i < 4096) { bs0[i] = bih0[i] + bhh0[i]; return; }
  i -= 4096;
  if (i < 4096) { bs1[i] = bih1[i] + bhh1[i]; return; }
  i -= 4096;
  if (i < 2097152) {
    int o = (int)i;
    int r = o & 511, tile = o >> 9;
    int q = r >> 7, rl = (r >> 3) & 15, j = r & 7;
    int kb = tile & 1, v = tile >> 1;
    int grt = v & 15, t = v >> 4;
    int row = grt * 16 + rl, k = kb * 32 + q * 8 + j;
    xf[o] = f2b(x[((size_t)t * BATCH + row) * 64 + k]);
    return;
  }
  i -= 2097152;
  if (i < 262144) {   // h0m slot 0: MASKED initial h0 (layer0 recurrent input @ t=0)
    int o = (int)i;
    int r = o & 511, tile = o >> 9;
    int q = r >> 7, rl = (r >> 3) & 15, j = r & 7;
    int grt = tile >> 5, kb = tile & 31;
    int row = grt * 16 + rl, h = kb * 32 + q * 8 + j;
    h0m[o] = done[row] ? (u16)0 : f2b(h0in[(size_t)row * HID + h]);
    return;
  }
  i -= 262144;
  if (i < 262144) {   // h1m slot 0: MASKED initial h1 (layer1 recurrent input @ t=0)
    int o = (int)i;
    int r = o & 511, tile = o >> 9;
    int q = r >> 7, rl = (r >> 3) & 15, j = r & 7;
    int grt = tile >> 5, kb = tile & 31;
    int row = grt * 16 + rl, h = kb * 32 + q * 8 + j;
    h1m[o] = done[row] ? (u16)0 : f2b(h0in[LSZ + (size_t)row * HID + h]);
    return;
  }
  i -= 262144;
  if (i < LSZ) { c0buf[i] = c0in[i]; return; }
  i -= LSZ;
  if (i < LSZ) { c1buf[i] = c0in[LSZ + i]; return; }
  i -= LSZ;
  if (i < 65536) { w2b[i] = f2b(w2[i]); return; }
  i -= 65536;
  if (i < 8192) { w3b[i] = f2b(w3[i]); return; }
  i -= 8192;
  if (i < 512) { flg[i] = 0; return; }
}

// ---------------- persistent LSTM recurrence ----------------
// 512 blocks x 256 thr -> 2 blocks/CU. bid = layer*256 + rg*32 + cg.
// block tile 32 rows x 128 gate-cols; wave wv owns 32-col slice (B dedup'd).
// 8-kb chunks (256 k): NC0=5, NC1=8. Per chunk per wave: 16 B reg-loads (depth 1),
// 4 A global_load_lds (depth 2 -> ~2 chunk-bodies of latency tolerance).
// One static s_waitcnt vmcnt(24) + raw s_barrier per chunk; all loop VMEM is
// compiler-tracked (GLDS builtin + C++ loads) so no hidden vmcnt(0) drains.
__global__ __launch_bounds__(256, 2) void lstm_persist(
    const u16* __restrict__ w0f, const u16* __restrict__ w1f, const u16* __restrict__ xf,
    u16* __restrict__ h0u, u16* __restrict__ h1u,
    u16* __restrict__ h0m, u16* __restrict__ h1m,
    float* __restrict__ c0b, float* __restrict__ c1b,
    const float* __restrict__ bs0, const float* __restrict__ bs1,
    const int* __restrict__ done, int* __restrict__ flg,
    float* __restrict__ dout)
{
  const int bid = blockIdx.x;
  const int layer = bid >> 8;
  const int rg = (bid >> 5) & 7;
  const int cg = bid & 31;
  const int tid = threadIdx.x;
  const int lane = tid & 63, wv = tid >> 6;
  const int quad = lane >> 4, c16 = lane & 15;
  const int NKB = layer ? 64 : 34;
  const int NC  = layer ? 8 : 5;    // ceil(NKB/8)
  const u16* Wf = layer ? w1f : w0f;
  const float* bs = layer ? bs1 : bs0;
  float* cb = layer ? c1b : c0b;
  int* fl0 = flg;
  int* fl1 = flg + 256;
  int* myf = (layer ? fl1 : fl0) + rg * 32 + cg;
  int* g0 = fl0 + rg * 32;
  int* g1 = fl1 + rg * 32;

  __shared__ __align__(16) u16 smem[32768];  // 4 x 16KB A chunk-buffers; epilogue gl aliases
  float* gl = (float*)smem;                  // 32 x 132 fp32 (padded stride)

  const short8 z8 = {0,0,0,0,0,0,0,0};

  for (int t = 0; t < SEQ; ++t) {
    // step-top waits; pipeline is empty here so any drain is free
    if (layer == 0) {
      if (t >= 1) waitgroup(g0, t);        // siblings' h0m(t-1) ready
    } else {
      waitgroup(g0, t + 1);                // h0u(t) ready (binding)
      if (t >= 1) waitgroup(g1, t);        // siblings' h1m(t-1) ready + WAR
    }

    // A chunk oc: kb in [oc*8, oc*8+8); wave wv stages kbl = wv and wv+4,
    // 2 grt tiles each -> 4 GLDS/wave. LDS buf (p&3): tile (kbl,j) at (kbl*2+j)*512 u16.
    auto issueA = [&](int p) {
      int oc = p; if (oc > NC - 1) oc = NC - 1;   // clamp dummies: counts stay static
      u16* lb = &smem[((unsigned)(p & 3)) * 8192];
      #pragma unroll
      for (int s = 0; s < 2; ++s) {
        int kbl = wv + s * 4;
        int kb = oc * 8 + kbl; if (kb > NKB - 1) kb = NKB - 1;
        u16* lt = lb + (unsigned)(kbl * 2) * 512;
        if (layer == 0) {
          if (kb < 2) {
            #pragma unroll
            for (int j = 0; j < 2; ++j) {
              const u16* g = xf + ((size_t)((t * 16 + rg * 2 + j) * 2 + kb)) * 512 + lane * 8;
              GLDS_NC(g, lt + j * 512);
            }
          } else {
            #pragma unroll
            for (int j = 0; j < 2; ++j) {
              const u16* g = h0m + (size_t)(t & 1) * 262144
                                 + (size_t)((rg * 2 + j) * 32 + (kb - 2)) * 512 + lane * 8;
              GLDS_CG(g, lt + j * 512);
            }
          }
        } else {
          if (kb < 32) {
            #pragma unroll
            for (int j = 0; j < 2; ++j) {
              const u16* g = h0u + (size_t)((t + 1) & 1) * 262144
                                 + (size_t)((rg * 2 + j) * 32 + kb) * 512 + lane * 8;
              GLDS_CG(g, lt + j * 512);
            }
          } else {
            #pragma unroll
            for (int j = 0; j < 2; ++j) {
              const u16* g = h1m + (size_t)(t & 1) * 262144
                                 + (size_t)((rg * 2 + j) * 32 + (kb - 32)) * 512 + lane * 8;
              GLDS_CG(g, lt + j * 512);
            }
          }
        }
      }
    };

    auto loadB = [&](int p, short8 (&vB)[8][2]) {
      int oc = p; if (oc > NC - 1) oc = NC - 1;
      #pragma unroll
      for (int kbl = 0; kbl < 8; ++kbl) {
        int kb = oc * 8 + kbl; if (kb > NKB - 1) kb = NKB - 1;
        #pragma unroll
        for (int h = 0; h < 2; ++h)
          vB[kbl][h] = *(const short8*)(Wf + ((size_t)(cg * NKB + kb) * 8 + wv * 2 + h) * 512 + lane * 8);
      }
    };

    f32x4 acc[2][2];
    #pragma unroll
    for (int a = 0; a < 2; ++a) { acc[a][0] = (f32x4){0,0,0,0}; acc[a][1] = (f32x4){0,0,0,0}; }

    auto comp = [&](int p, short8 (&vB)[8][2]) {
      int kbc = NKB - p * 8; if (kbc > 8) kbc = 8;
      const u16* sb = &smem[((unsigned)(p & 3)) * 8192] + lane * 8;
      #pragma unroll
      for (int kbl = 0; kbl < 8; ++kbl) if (kbl < kbc) {
        #pragma unroll
        for (int a = 0; a < 2; ++a) {
          short8 af = *(const short8*)(sb + (kbl * 2 + a) * 512);
          acc[a][0] = MFMA(af, vB[kbl][0], acc[a][0]);
          acc[a][1] = MFMA(af, vB[kbl][1], acc[a][1]);
        }
      }
    };

    short8 vB0[8][2], vB1[8][2];

    // prologue queue: [B(0) 16][A(0) 4][A(1) 4] = 24 outstanding
    loadB(0, vB0);
    asm volatile("" ::: "memory");
    issueA(0);
    asm volatile("" ::: "memory");
    issueA(1);

    // iter c: +[B(c+1) 16][A(c+2) 4] -> 44 in flight; vmcnt(24) drains the
    // oldest 20 = exactly iter(c-1)'s B(c)+A(c+1); comp(c)'s A(c) is older still.
#define CHUNK(CC, VBL, VBU) \
    loadB((CC) + 1, VBL); \
    asm volatile("" ::: "memory"); \
    issueA((CC) + 2); \
    asm volatile("s_waitcnt vmcnt(24)" ::: "memory"); \
    __builtin_amdgcn_s_barrier(); \
    __builtin_amdgcn_sched_barrier(0); \
    comp((CC), VBU);

    int c = 0;
    for (;;) {
      CHUNK(c, vB1, vB0) if (++c == NC) break;
      CHUNK(c, vB0, vB1) if (++c == NC) break;
    }
#undef CHUNK

    // drain dummy prefetches before aliasing smem as gl; sync all waves' comp
    wait_vm0();
    __syncthreads();

    // epilogue: gates -> LDS gl[row32][132]; wave wv owns cols [wv*32, wv*32+32)
    #pragma unroll
    for (int a = 0; a < 2; ++a)
      #pragma unroll
      for (int ct = 0; ct < 2; ++ct)
        #pragma unroll
        for (int rgi = 0; rgi < 4; ++rgi)
          gl[(a * 16 + quad * 4 + rgi) * 132 + wv * 32 + ct * 16 + c16] = acc[a][ct][rgi];
    __syncthreads();

    // L0's WAR wait (guards only the h0u/h0m stores below)
    if (layer == 0 && t >= 2) waitgroup(g1, t - 1);

    if (tid < 128) {
      int row = tid >> 2;           // 0..31
      int q = tid & 3;
      int h8 = q * 8;
      int rowg = rg * 32 + row;
      int H0 = cg * 32 + h8;
      const float* glp = gl + row * 132;
      float m = done[t * BATCH + rowg] ? 0.f : 1.f;
      int nx = (t < SEQ - 1) ? done[(t + 1) * BATCH + rowg] : 0;
      float* cp = cb + (size_t)rowg * HID + H0;
      short8 hv;
      float h2a[8], c2a[8];
      #pragma unroll
      for (int j = 0; j < 8; ++j) {
        float ivv = glp[h8 + j]      + bs[H0 + j];
        float fvv = glp[32 + h8 + j] + bs[HID + H0 + j];
        float gvv = glp[64 + h8 + j] + bs[2*HID + H0 + j];
        float ovv = glp[96 + h8 + j] + bs[3*HID + H0 + j];
        float c2 = sigm(fvv) * (cp[j] * m) + sigm(ivv) * tanh_f(gvv);
        float h2 = sigm(ovv) * tanh_f(c2);
        cp[j] = c2;
        h2a[j] = h2; c2a[j] = c2;
        ((u16*)&hv)[j] = f2b(h2);
      }
      short8 hm = nx ? z8 : hv;
      size_t off = (size_t)((rg * 2 + (row >> 4)) * 32 + cg) * 512 + (size_t)(q * 16 + (row & 15)) * 8;
      if (layer == 0) {
        store_cg(h0u + (size_t)((t + 1) & 1) * 262144 + off, hv);
        if (t < SEQ - 1) store_cg(h0m + (size_t)((t + 1) & 1) * 262144 + off, hm);
      } else {
        store_cg(h1u + (size_t)(t + 1) * 262144 + off, hv);
        if (t < SEQ - 1) store_cg(h1m + (size_t)((t + 1) & 1) * 262144 + off, hm);
      }
      if (t == SEQ - 1) {
        float* dh = dout + 32768 + (size_t)layer * LSZ + (size_t)rowg * HID + H0;
        float* dc = dout + 32768 + 2 * LSZ + (size_t)layer * LSZ + (size_t)rowg * HID + H0;
        #pragma unroll
        for (int j = 0; j < 8; ++j) { dh[j] = h2a[j]; dc[j] = c2a[j]; }
      }
    }
    wait_vm0();
    __syncthreads();
    if (tid == 0) __hip_atomic_fetch_add(myf, 1, __ATOMIC_RELAXED, __HIP_MEMORY_SCOPE_AGENT);
  }
}

// ---------------- LayerNorm row stats (reads h1u frag layout) ----------------
__global__ void ln_stats(const u16* __restrict__ h1u, float* __restrict__ mu, float* __restrict__ rstd) {
  int R = blockIdx.x * 4 + (threadIdx.x >> 6);
  int l = threadIdx.x & 63;
  int t = R >> 8, brow = R & 255, grt = brow >> 4, rl = brow & 15;
  const u16* base = h1u + (size_t)(t + 1) * 262144 + (size_t)(grt * 32 + (l >> 1)) * 512;
  int q2 = (l & 1) * 2;
  short8 v0 = *(const short8*)(base + (q2 * 16 + rl) * 8);
  short8 v1 = *(const short8*)(base + ((q2 + 1) * 16 + rl) * 8);
  float s = 0.f, q = 0.f;
  #pragma unroll
  for (int e = 0; e < 8; ++e) {
    float a = b2f((u16)v0[e]); s += a; q += a*a;
    float b = b2f((u16)v1[e]); s += b; q += b*b;
  }
  for (int o = 32; o > 0; o >>= 1) { s += __shfl_xor(s, o); q += __shfl_xor(q, o); }
  if (l == 0) {
    float mm = s * (1.f/1024.f);
    float var = q * (1.f/1024.f) - mm*mm;
    mu[R] = mm; rstd[R] = rsqrtf(var + 1e-5f);
  }
}

// ---------------- MLP GEMM: 128x128 tile, amode1 = A in h1u frag layout ----------------
__global__ __launch_bounds__(512, 4) void mlp_gemm(
    const u16* __restrict__ A, int lda, int amode,
    const u16* __restrict__ B, int K, int N,
    u16* __restrict__ out, int ldo, int mode, int swiz,
    const float* __restrict__ mu, const float* __restrict__ rstd,
    const float* __restrict__ S1v, const float* __restrict__ bias)
{
  int nt, mtb;
  if (swiz) { int p = blockIdx.x * gridDim.y + blockIdx.y; nt = p & 3; mtb = p >> 2; }
  else { nt = blockIdx.x; mtb = blockIdx.y; }
  const int tid = threadIdx.x, lane = tid & 63, wv = tid >> 6;
  const int quad = lane >> 4, c16 = lane & 15;
  __shared__ __align__(16) u16 Am[16384], Bm[16384];
  f32x4 acc[8];
  #pragma unroll
  for (int i = 0; i < 8; ++i) acc[i] = (f32x4){0.f,0.f,0.f,0.f};

  int arow[4], akl[4], bcol[4];
  #pragma unroll
  for (int i = 0; i < 4; ++i) {
    int s = tid + i * 512, sub = s >> 6, lp = s & 63;
    int ks = sub >> 3, u = sub & 7;
    arow[i] = mtb * 128 + u * 16 + (lp & 15);
    akl[i]  = ks * 32 + (lp >> 4) * 8;
    bcol[i] = nt * 128 + u * 16 + (lp & 15);
  }
  short8 vA[4], vB[4];
  const short8 z8 = {0,0,0,0,0,0,0,0};
  const int NCH = K >> 7;
  auto load_stage = [&](int ci) {
    int kc = ci << 7;
    #pragma unroll
    for (int i = 0; i < 4; ++i) {
      if (amode) {
        int R = arow[i], k = kc + akl[i];
        const u16* p = A + (size_t)((R >> 8) + 1) * 262144
                         + (size_t)(((R >> 4) & 15) * 32 + (k >> 5)) * 512
                         + (size_t)((((k >> 3) & 3) * 16 + (R & 15)) * 8);
        vA[i] = *(const short8*)p;
      } else {
        vA[i] = *(const short8*)(A + (size_t)arow[i] * lda + kc + akl[i]);
      }
      vB[i] = (bcol[i] < N) ? *(const short8*)(B + (size_t)bcol[i] * K + kc + akl[i]) : z8;
    }
  };
  load_stage(0);
  for (int ci = 0; ci < NCH; ++ci) {
    #pragma unroll
    for (int i = 0; i < 4; ++i) {
      *(short8*)&Am[(size_t)(tid + i*512) * 8] = vA[i];
      *(short8*)&Bm[(size_t)(tid + i*512) * 8] = vB[i];
    }
    __syncthreads();
    if (ci + 1 < NCH) load_stage(ci + 1);
    #pragma unroll
    for (int ks = 0; ks < 4; ++ks) {
      short8 bf = *(const short8*)&Bm[((ks*8 + wv)*64 + lane) * 8];
      #pragma unroll
      for (int rt = 0; rt < 8; ++rt) {
        short8 af = *(const short8*)&Am[((ks*8 + rt)*64 + lane) * 8];
        acc[rt] = MFMA(af, bf, acc[rt]);
      }
    }
    __syncthreads();
  }
  int col = nt * 128 + wv * 16 + c16;
  if (col < N) {
    #pragma unroll
    for (int rt = 0; rt < 8; ++rt) {
      #pragma unroll
      for (int rgi = 0; rgi < 4; ++rgi) {
        int row = mtb * 128 + rt * 16 + quad * 4 + rgi;
        float v = acc[rt][rgi];
        if (mode == 0) v = v * rstd[row] - mu[row] * rstd[row] * S1v[col] + bias[col];
        else           v = v + bias[col];
        v = eluf(v);
        out[(size_t)row * ldo + col] = f2b(v);
      }
    }
  }
}

__global__ void value_head(const u16* __restrict__ a3, const float* __restrict__ wv,
                           const float* __restrict__ bv, float* __restrict__ dout) {
  int row = blockIdx.x * 256 + threadIdx.x;
  const short8* p = (const short8*)(a3 + (size_t)row * 64);
  float s = bv[0];
  #pragma unroll
  for (int j = 0; j < 8; ++j) {
    short8 v = p[j];
    #pragma unroll
    for (int e = 0; e < 8; ++e) s += b2f((u16)v[e]) * wv[j*8+e];
  }
  dout[row] = s;
}

extern "C" void kernel_launch(void* const* d_in, const int* in_sizes, int n_in,
                              void* d_out, int out_size, void* d_ws, size_t ws_size,
                              hipStream_t stream) {
  (void)in_sizes; (void)n_in; (void)out_size; (void)ws_size;
  const float* x    = (const float*)d_in[0];
  const int*   done = (const int*)d_in[1];
  const float* h0in = (const float*)d_in[2];
  const float* c0in = (const float*)d_in[3];
  const float* wih0 = (const float*)d_in[4];
  const float* whh0 = (const float*)d_in[5];
  const float* bih0 = (const float*)d_in[6];
  const float* bhh0 = (const float*)d_in[7];
  const float* wih1 = (const float*)d_in[8];
  const float* whh1 = (const float*)d_in[9];
  const float* bih1 = (const float*)d_in[10];
  const float* bhh1 = (const float*)d_in[11];
  const float* lng  = (const float*)d_in[12];
  const float* lnb  = (const float*)d_in[13];
  const float* w1   = (const float*)d_in[14];
  const float* b1   = (const float*)d_in[15];
  const float* w2   = (const float*)d_in[16];
  const float* b2   = (const float*)d_in[17];
  const float* w3   = (const float*)d_in[18];
  const float* b3   = (const float*)d_in[19];
  const float* wvp  = (const float*)d_in[20];
  const float* bvp  = (const float*)d_in[21];
  float* dout = (float*)d_out;
  char* ws = (char*)d_ws;

  u16*   w0f  = (u16*)(ws + OFF_W0F);
  u16*   w1f  = (u16*)(ws + OFF_W1F);
  u16*   xf   = (u16*)(ws + OFF_XF);
  u16*   h0u  = (u16*)(ws + OFF_H0U);
  u16*   h1u  = (u16*)(ws + OFF_H1U);
  u16*   h0m  = (u16*)(ws + OFF_H0M);
  u16*   h1m  = (u16*)(ws + OFF_H1M);
  float* c0b  = (float*)(ws + OFF_C0);
  float* c1b  = (float*)(ws + OFF_C1);
  float* bs0  = (float*)(ws + OFF_BS0);
  float* bs1  = (float*)(ws + OFF_BS1);
  int*   flg  = (int*)(ws + OFF_MU);   // 512 flags; dead before ln_stats overwrites mu
  float* mu   = (float*)(ws + OFF_MU);
  float* rstd = (float*)(ws + OFF_RSTD);
  u16*   w1ln = (u16*)(ws + OFF_W1LN);
  float* s1   = (float*)(ws + OFF_S1);
  float* b1p  = (float*)(ws + OFF_B1P);
  u16*   w2b  = (u16*)(ws + OFF_W2B);
  u16*   w3b  = (u16*)(ws + OFF_W3B);
  u16*   a1   = (u16*)(ws + OFF_A1);
  u16*   a2   = (u16*)(ws + OFF_A2);
  u16*   a3   = (u16*)(ws + OFF_A3);

  prep_wf<<<256, 256, 0, stream>>>(wih0, whh0, w0f, 34, 64);
  prep_wf<<<256, 256, 0, stream>>>(wih1, whh1, w1f, 64, 1024);
  prep_w1ln<<<512, 256, 0, stream>>>(w1, lng, lnb, b1, w1ln, s1, b1p);
  prep_misc<<<12610, 256, 0, stream>>>(bih0, bhh0, bih1, bhh1, x, h0in, c0in, w2, w3, done,
                                       bs0, bs1, xf, h0m, h1m, c0b, c1b, w2b, w3b, flg);

  lstm_persist<<<512, 256, 0, stream>>>(w0f, w1f, xf, h0u, h1u, h0m, h1m, c0b, c1b,
                                        bs0, bs1, done, flg, dout);

  ln_stats<<<8192, 256, 0, stream>>>(h1u, mu, rstd);
  mlp_gemm<<<dim3(8, 128), 512, 0, stream>>>(h1u, 0, 1, w1ln, 1024, 512, a1, 512, 0, 1, mu, rstd, s1, b1p);
  mlp_gemm<<<dim3(1, 256), 512, 0, stream>>>(a1, 512, 0, w2b, 512, 128, a2, 128, 1, 0, mu, rstd, s1, b2);
  mlp_gemm<<<dim3(1, 256), 512, 0, stream>>>(a2, 128, 0, w3b, 128, 64, a3, 64, 1, 0, mu, rstd, s1, b3);
  value_head<<<128, 256, 0, stream>>>(a3, wvp, bvp, dout);
}